// Round 1
// baseline (33427.182 us; speedup 1.0000x reference)
//
#include <hip/hip_runtime.h>

// Problem constants (from reference)
#define B_      64
#define N_      307
#define S_TOTAL (B_ * N_)   // 19648 sequential LSTM steps
#define T_CH    12          // 12 independent chains ("batch" rows)
#define F_IN    3
#define HID     128
#define NGATE   (4 * HID)   // 512

__device__ __forceinline__ float fast_sigmoid(float v) {
    // rcp(1 + exp(-v)); exp overflow -> inf -> rcp -> 0 (correct limit)
    return __builtin_amdgcn_rcpf(1.0f + __expf(-v));
}
__device__ __forceinline__ float fast_tanh(float v) {
    // 2*sigmoid(2v) - 1; saturates correctly at +-1 for large |v|
    return 2.0f * __builtin_amdgcn_rcpf(1.0f + __expf(-2.0f * v)) - 1.0f;
}

// One block per chain t (12 blocks). 512 threads: one per gate output.
// W_hh row (128 floats) held in registers per thread; launch_bounds(512,2)
// caps VGPRs at 256 so the 8-wave block fits 2 waves/SIMD.
__global__ __launch_bounds__(NGATE, 2) void lstm_chain(
    const float* __restrict__ x,      // (B,N,F_IN,T_IN) flat: idx = s*36 + f*12 + t
    const float* __restrict__ W_ih,   // (512,3)
    const float* __restrict__ W_hh,   // (512,128)
    const float* __restrict__ b_ih,   // (512)
    const float* __restrict__ b_hh,   // (512)
    const float* __restrict__ W_lin,  // (128)
    const float* __restrict__ b_lin,  // (1)
    float* __restrict__ out)          // (S,12) flat: s*12 + t
{
    const int t = blockIdx.x;    // chain id 0..11
    const int g = threadIdx.x;   // gate id 0..511

    __shared__ __align__(16) float h_sh[HID];
    __shared__ float zi_sh[HID];
    __shared__ float zf_sh[HID];
    __shared__ float zg_sh[HID];
    __shared__ float zo_sh[HID];

    // Per-thread recurrent weights in registers (fully unrolled use keeps
    // them in VGPRs: 128 regs).
    float w[HID];
#pragma unroll
    for (int k = 0; k < HID; k += 4) {
        float4 wv = *(const float4*)&W_hh[g * HID + k];
        w[k] = wv.x; w[k + 1] = wv.y; w[k + 2] = wv.z; w[k + 3] = wv.w;
    }
    const float wi0  = W_ih[g * F_IN + 0];
    const float wi1  = W_ih[g * F_IN + 1];
    const float wi2  = W_ih[g * F_IN + 2];
    const float bias = b_ih[g] + b_hh[g];

    // Wave 0 also owns the (deferred-by-one) output dot: thread j holds
    // W_lin[2j], W_lin[2j+1].
    float wl0 = 0.0f, wl1 = 0.0f;
    const float blin = b_lin[0];
    if (g < 64) { wl0 = W_lin[2 * g]; wl1 = W_lin[2 * g + 1]; }

    float c = 0.0f;              // cell state, owned by threads 0..127
    if (g < HID) h_sh[g] = 0.0f; // h_{-1} = 0

    // Prefetch x for step 0 (3 broadcast floats)
    float xp0 = x[t];
    float xp1 = x[12 + t];
    float xp2 = x[24 + t];

    __syncthreads();

    for (int s = 0; s < S_TOTAL; ++s) {
        const float x0 = xp0, x1 = xp1, x2 = xp2;
        // Prefetch x for s+1; vmcnt drain at the next barrier is ~500 cyc
        // after issue -> hidden. Clamp to stay in bounds on last step.
        const int  sn   = (s + 1 < S_TOTAL) ? (s + 1) : s;
        const long base = (long)sn * 36 + t;
        xp0 = x[base];
        xp1 = x[base + 12];
        xp2 = x[base + 24];

        // z[g] = bias + x . W_ih[g,:] + h_{s-1} . W_hh[g,:]
        float a0 = __builtin_fmaf(x0, wi0, bias);
        a0 = __builtin_fmaf(x1, wi1, a0);
        a0 = __builtin_fmaf(x2, wi2, a0);
        float a1 = 0.0f, a2 = 0.0f, a3 = 0.0f;
#pragma unroll
        for (int k = 0; k < HID; k += 4) {
            // broadcast read: all lanes same address -> conflict-free
            float4 hv = *(const float4*)&h_sh[k];
            a0 = __builtin_fmaf(hv.x, w[k],     a0);
            a1 = __builtin_fmaf(hv.y, w[k + 1], a1);
            a2 = __builtin_fmaf(hv.z, w[k + 2], a2);
            a3 = __builtin_fmaf(hv.w, w[k + 3], a3);
        }
        const float acc = (a0 + a1) + (a2 + a3);

        // Wave 0: out[s-1] = h_{s-1} . W_lin + b_lin (h_sh still = h_{s-1})
        if (g < 64) {
            float2 hp  = *(const float2*)&h_sh[2 * g];
            float pout = __builtin_fmaf(hp.x, wl0, hp.y * wl1);
#pragma unroll
            for (int off = 32; off >= 1; off >>= 1)
                pout += __shfl_xor(pout, off, 64);
            if (g == 0 && s > 0) out[(s - 1) * T_CH + t] = pout + blin;
        }

        // Per-gate nonlinearity on the owning thread (wave-uniform branches),
        // publish transformed gates. Gate order: [i | f | g(tanh) | o].
        if (g < 128)      zi_sh[g]       = fast_sigmoid(acc);
        else if (g < 256) zf_sh[g - 128] = fast_sigmoid(acc);
        else if (g < 384) zg_sh[g - 256] = fast_tanh(acc);
        else              zo_sh[g - 384] = fast_sigmoid(acc);

        __syncthreads();  // gates ready; also fences h_sh readers before overwrite

        if (g < HID) {
            const float cn = __builtin_fmaf(zf_sh[g], c, zi_sh[g] * zg_sh[g]);
            c = cn;
            h_sh[g] = zo_sh[g] * fast_tanh(cn);   // h_s published
        }
        __syncthreads();  // h_s visible to all for next step
    }

    // Epilogue: out[S-1] from the final h
    if (g < 64) {
        float2 hp  = *(const float2*)&h_sh[2 * g];
        float pout = __builtin_fmaf(hp.x, wl0, hp.y * wl1);
#pragma unroll
        for (int off = 32; off >= 1; off >>= 1)
            pout += __shfl_xor(pout, off, 64);
        if (g == 0) out[(S_TOTAL - 1) * T_CH + t] = pout + blin;
    }
}

extern "C" void kernel_launch(void* const* d_in, const int* in_sizes, int n_in,
                              void* d_out, int out_size, void* d_ws, size_t ws_size,
                              hipStream_t stream) {
    const float* x     = (const float*)d_in[0];
    const float* W_ih  = (const float*)d_in[1];
    const float* W_hh  = (const float*)d_in[2];
    const float* b_ih  = (const float*)d_in[3];
    const float* b_hh  = (const float*)d_in[4];
    const float* W_lin = (const float*)d_in[5];
    const float* b_lin = (const float*)d_in[6];
    float* out = (float*)d_out;

    hipLaunchKernelGGL(lstm_chain, dim3(T_CH), dim3(NGATE), 0, stream,
                       x, W_ih, W_hh, b_ih, b_hh, W_lin, b_lin, out);
}

// Round 2
// 19906.075 us; speedup vs baseline: 1.6792x; 1.6792x over previous
//
#include <hip/hip_runtime.h>

// Problem constants (from reference)
#define S_TOTAL 19648      // B*N sequential LSTM steps
#define T_CH    12         // independent chains
#define HID     128
#define NTHREADS 1024

// LDS h-tilde buffer layout (per buffer):
//   8 chunks of 20 floats (16 h-values + 4 pad) -> swizzle so each octant's
//   ds_read_b128 base lands on a distinct bank quad (banks 20o mod 32:
//   {0,20,8,28,16,4,24,12} -> conflict-free broadcast reads).
//   ext slots [160..167]: [160..162]=x0..x2, [163]=1.0 (bias lane), [164..167]=0
#define BUFSZ   176
#define EXT_OFF 160

__device__ __forceinline__ int hslot_of(int idx) {
    return ((idx >> 4) * 20) + (idx & 15);
}

// One block per chain (12 blocks), 1024 threads.
// tid = j*8 + o: j = h-index (0..127), o = k-octant (0..7).
// Thread holds W_hh rows {q*128+j} restricted to k in [16o,16o+16) -> 64 regs,
// plus one extended-k weight per gate (x / bias slot) -> 68 weight VGPRs.
__global__ __launch_bounds__(NTHREADS, 4) void lstm_chain(
    const float* __restrict__ x,      // (S,3,12) flat: s*36 + f*12 + t
    const float* __restrict__ W_ih,   // (512,3)
    const float* __restrict__ W_hh,   // (512,128)
    const float* __restrict__ b_ih,   // (512)
    const float* __restrict__ b_hh,   // (512)
    const float* __restrict__ W_lin,  // (128)
    const float* __restrict__ b_lin,  // (1)
    float* __restrict__ out)          // (S,12) flat: s*12 + t
{
    const int t   = blockIdx.x;
    const int tid = threadIdx.x;
    const int j   = tid >> 3;   // h index
    const int o   = tid & 7;    // k octant

    __shared__ __align__(16) float bufs[2 * BUFSZ];

    // ---- load weights into registers (one-time) ----
    float w[4][16];   // gate q, k = 16o+m
    float wt[4];      // extended-k weight (slot 160+o): x-weights / bias / 0
#pragma unroll
    for (int q = 0; q < 4; ++q) {
        const int row = q * HID + j;
        const float* wr = &W_hh[row * HID + 16 * o];
#pragma unroll
        for (int mm = 0; mm < 4; ++mm) {
            float4 v = *(const float4*)&wr[4 * mm];
            w[q][4 * mm + 0] = v.x;
            w[q][4 * mm + 1] = v.y;
            w[q][4 * mm + 2] = v.z;
            w[q][4 * mm + 3] = v.w;
        }
        float tw = 0.0f;
        if (o < 3)       tw = W_ih[row * 3 + o];          // x_o weight
        else if (o == 3) tw = b_ih[row] + b_hh[row];      // bias (slot holds 1.0)
        wt[q] = tw;
    }

    // Wave 1 owns the (deferred-by-one) output dot.
    float wl0 = 0.0f, wl1 = 0.0f;
    const float blin = b_lin[0];
    const int L = tid - 64;   // meaningful for tid in [64,128)
    if (tid >= 64 && tid < 128) { wl0 = W_lin[2 * L]; wl1 = W_lin[2 * L + 1]; }

    const int hslot = hslot_of(j);
    const int chunk = 20 * o;

    // ---- init LDS buffers ----
    if (tid < HID) bufs[hslot_of(tid)] = 0.0f;   // h_{-1} = 0 in buf0
    if (tid == 3) { bufs[EXT_OFF + 3] = 1.0f; bufs[BUFSZ + EXT_OFF + 3] = 1.0f; }
    if (tid >= 4 && tid < 8) { bufs[EXT_OFF + tid] = 0.0f; bufs[BUFSZ + EXT_OFF + tid] = 0.0f; }
    if (tid < 3) bufs[EXT_OFF + tid] = x[tid * 12 + t];   // x for s=0
    float c = 0.0f;
    __syncthreads();

    for (int s = 0; s < S_TOTAL; ++s) {
        float* cur = &bufs[(s & 1) * BUFSZ];          // holds h~_{s-1}
        float* nxt = &bufs[((s & 1) ^ 1) * BUFSZ];    // receives h~_s

        // Prefetch x for step s+1 (3 lanes of wave 0); ds_write before barrier.
        float xr = 0.0f;
        if (tid < 3) {
            const int sn = (s + 1 < S_TOTAL) ? (s + 1) : s;
            xr = x[sn * 36 + tid * 12 + t];
        }

        // ---- partial dots: 4 gates x 17 k-elems ----
        const float tail = cur[EXT_OFF + o];
        const float4 h0 = *(const float4*)&cur[chunk + 0];
        const float4 h1 = *(const float4*)&cur[chunk + 4];
        const float4 h2 = *(const float4*)&cur[chunk + 8];
        const float4 h3 = *(const float4*)&cur[chunk + 12];
        float hv[16] = {h0.x, h0.y, h0.z, h0.w, h1.x, h1.y, h1.z, h1.w,
                        h2.x, h2.y, h2.z, h2.w, h3.x, h3.y, h3.z, h3.w};

        float a0 = wt[0] * tail;
        float a1 = wt[1] * tail;
        float a2 = wt[2] * tail;
        float a3 = wt[3] * tail;
#pragma unroll
        for (int m = 0; m < 16; ++m) {
            a0 = __builtin_fmaf(hv[m], w[0][m], a0);
            a1 = __builtin_fmaf(hv[m], w[1][m], a1);
            a2 = __builtin_fmaf(hv[m], w[2][m], a2);
            a3 = __builtin_fmaf(hv[m], w[3][m], a3);
        }

        // ---- butterfly across the 8-lane j-group: all lanes get all 4 sums ----
#pragma unroll
        for (int mk = 1; mk <= 4; mk <<= 1) {
            a0 += __shfl_xor(a0, mk, 64);
            a1 += __shfl_xor(a1, mk, 64);
            a2 += __shfl_xor(a2, mk, 64);
            a3 += __shfl_xor(a3, mk, 64);
        }

        // ---- distributed transcendentals (lane-role o&3 does one gate) ----
        const int o2 = o & 3;
        const float arg = (o2 == 0) ? a0 : (o2 == 1) ? a1 : (o2 == 2) ? a2 : a3;
        const float sc  = (o2 == 2) ? -2.0f : -1.0f;
        const float e   = __expf(arg * sc);
        const float r   = __builtin_amdgcn_rcpf(1.0f + e);
        const float val = (o2 == 2) ? __builtin_fmaf(2.0f, r, -1.0f) : r;  // tanh vs sigmoid
        // reassemble on role-0 lanes: val=zi, vf=zf, vg=zg, vo=zo
        const float vf = __shfl_xor(val, 1, 64);
        const float vg = __shfl_xor(val, 2, 64);
        const float vo = __shfl_xor(val, 3, 64);
        const float cn = __builtin_fmaf(vf, c, val * vg);
        c = cn;                                   // meaningful on o==0 (and o==4) lanes
        const float e2 = __expf(-2.0f * cn);
        const float th = __builtin_fmaf(2.0f, __builtin_amdgcn_rcpf(1.0f + e2), -1.0f);
        const float hn = vo * th;
        if (o == 0) nxt[hslot] = hn;              // publish h_s
        if (tid < 3) nxt[EXT_OFF + tid] = xr;     // publish x_{s+1}

        // ---- wave 1: out[s-1] = h_{s-1} . W_lin + b_lin (cur still h_{s-1}) ----
        if (tid >= 64 && tid < 128) {
            const int p0 = 2 * L;
            const int sl = hslot_of(p0);          // p0 even -> sl+1 is p0+1's slot
            const float hv0 = cur[sl];
            const float hv1 = cur[sl + 1];
            float po = __builtin_fmaf(hv0, wl0, hv1 * wl1);
#pragma unroll
            for (int mk = 32; mk >= 1; mk >>= 1) po += __shfl_xor(po, mk, 64);
            if (tid == 64 && s > 0) out[(s - 1) * T_CH + t] = po + blin;
        }

        __syncthreads();   // h_s / x_{s+1} visible; cur free for overwrite next step
    }

    // ---- epilogue: out[S-1] ----
    {
        const float* fin = &bufs[(S_TOTAL & 1) * BUFSZ];
        if (tid >= 64 && tid < 128) {
            const int p0 = 2 * L;
            const int sl = hslot_of(p0);
            const float hv0 = fin[sl];
            const float hv1 = fin[sl + 1];
            float po = __builtin_fmaf(hv0, wl0, hv1 * wl1);
#pragma unroll
            for (int mk = 32; mk >= 1; mk >>= 1) po += __shfl_xor(po, mk, 64);
            if (tid == 64) out[(S_TOTAL - 1) * T_CH + t] = po + blin;
        }
    }
}

extern "C" void kernel_launch(void* const* d_in, const int* in_sizes, int n_in,
                              void* d_out, int out_size, void* d_ws, size_t ws_size,
                              hipStream_t stream) {
    const float* x     = (const float*)d_in[0];
    const float* W_ih  = (const float*)d_in[1];
    const float* W_hh  = (const float*)d_in[2];
    const float* b_ih  = (const float*)d_in[3];
    const float* b_hh  = (const float*)d_in[4];
    const float* W_lin = (const float*)d_in[5];
    const float* b_lin = (const float*)d_in[6];
    float* out = (float*)d_out;

    hipLaunchKernelGGL(lstm_chain, dim3(T_CH), dim3(NTHREADS), 0, stream,
                       x, W_ih, W_hh, b_ih, b_hh, W_lin, b_lin, out);
}